// Round 13
// baseline (146.247 us; speedup 1.0000x reference)
//
#include <hip/hip_runtime.h>
#include <hip/hip_bf16.h>

// Problem constants (GraphConv: B=4, C=64, N=16384, K=32)
#define BB 4
#define CC 64
#define NN 16384
#define KK 32
#define PTS (BB * NN)   // 65536 points
#define NP  2048        // BN partial slots (32 points each)

typedef __bf16 bf16x8 __attribute__((ext_vector_type(8)));
typedef float  f32x4  __attribute__((ext_vector_type(4)));
typedef unsigned uint32x4 __attribute__((ext_vector_type(4)));
typedef _Float16 f16x2 __attribute__((ext_vector_type(2)));

// ---- pack/convert helpers --------------------------------------------------
static __device__ __forceinline__ unsigned short f2bf(float f) {
    unsigned u = __builtin_bit_cast(unsigned, f);
    unsigned r = (u + 0x7fffu + ((u >> 16) & 1u)) >> 16;   // round-nearest-even
    return (unsigned short)r;
}
static __device__ __forceinline__ float bf2f(unsigned short h) {
    return __builtin_bit_cast(float, (unsigned)h << 16);
}
static __device__ __forceinline__ unsigned short f2h(float f) {
    return __builtin_bit_cast(unsigned short, (_Float16)f);   // v_cvt_f16_f32 RNE
}
static __device__ __forceinline__ bf16x8 pack8(const float* v) {
    uint32x4 u;
#pragma unroll
    for (int i = 0; i < 4; ++i)
        u[i] = (unsigned)f2bf(v[2 * i]) | ((unsigned)f2bf(v[2 * i + 1]) << 16);
    return __builtin_bit_cast(bf16x8, u);
}

// ---------------------------------------------------------------------------
// k1 (v5, MFMA): zt[bl][n][o] (fp16x2-packed) = sum_c W[o][c]*x[b][c][n].
//   MFMA math unchanged from v4 (bf16 hi/lo split of W compensates W's
//   rounding). Output now packed fp16 (10-bit mantissa beats bf16's 7 ->
//   absmax improves) so k3 can accumulate with packed v_pk_add_f16.
// ---------------------------------------------------------------------------
template <int ZB>
__global__ __launch_bounds__(256) void k1_wx_t(const float* __restrict__ x,
                                               const float* __restrict__ W,
                                               unsigned* __restrict__ ztu,
                                               int b0) {
    __shared__ float    xs[64 * 65];     // 16.6 KB fp32 x chunk
    __shared__ unsigned zsu[64 * 33];    // 8.4 KB fp16x2 output tile
    const int tid  = threadIdx.x;
    const int lane = tid & 63;
    const int w    = tid >> 6;
    const int chunk = blockIdx.x;        // ZB*256 chunks of 64 points
    const int bl = (ZB == 4) ? (chunk >> 8) : 0;
    const int b  = b0 + bl;
    const int n0 = (chunk & 255) << 6;

    const int ln = lane & 15;            // MFMA row (A: o) / col (B,D: n)
    const int lg = lane >> 4;            // MFMA k-group (A,B) / row-group (D)

    // A fragments: o = 16w+ln, c = k0 + lg*8 + j. hi = bf16(W), lo = bf16(W-hi).
    bf16x8 a_hi[2], a_lo[2];
    {
        const float* wr = W + (16 * w + ln) * 64 + lg * 8;
#pragma unroll
        for (int h = 0; h < 2; ++h) {
            float vhi[8], vlo[8];
#pragma unroll
            for (int j = 0; j < 8; ++j) {
                const float v  = wr[h * 32 + j];
                const float fh = bf2f(f2bf(v));
                vhi[j] = fh;
                vlo[j] = v - fh;
            }
            a_hi[h] = pack8(vhi);
            a_lo[h] = pack8(vlo);
        }
    }

    // stage x[b][0:64][n0:n0+64] (coalesced 256B rows), fp32
    const float* xb = x + (size_t)b * CC * NN + n0;
#pragma unroll
    for (int i = 0; i < 16; ++i) {
        const int c = i * 4 + w;
        xs[c * 65 + lane] = xb[(size_t)c * NN + lane];
    }
    __syncthreads();

    // 4 n-subtiles x (k0=0,32) x (hi,lo) MFMAs
    f32x4 acc[4];
#pragma unroll
    for (int nt = 0; nt < 4; ++nt) acc[nt] = {0.f, 0.f, 0.f, 0.f};

#pragma unroll
    for (int nt = 0; nt < 4; ++nt) {
#pragma unroll
        for (int h = 0; h < 2; ++h) {
            float bv[8];
#pragma unroll
            for (int j = 0; j < 8; ++j)      // x[c = 32h + lg*8 + j][n0+nt*16+ln]
                bv[j] = xs[(32 * h + lg * 8 + j) * 65 + nt * 16 + ln];
            const bf16x8 bfrag = pack8(bv);
            acc[nt] = __builtin_amdgcn_mfma_f32_16x16x32_bf16(a_hi[h], bfrag, acc[nt], 0, 0, 0);
            acc[nt] = __builtin_amdgcn_mfma_f32_16x16x32_bf16(a_lo[h], bfrag, acc[nt], 0, 0, 0);
        }
    }

    // epilogue: lane holds z[o = 16w + lg*4 + r][n = n0 + nt*16 + ln], r=0..3
#pragma unroll
    for (int nt = 0; nt < 4; ++nt) {
        const unsigned p0 = (unsigned)f2h(acc[nt][0]) | ((unsigned)f2h(acc[nt][1]) << 16);
        const unsigned p1 = (unsigned)f2h(acc[nt][2]) | ((unsigned)f2h(acc[nt][3]) << 16);
        const int base = (nt * 16 + ln) * 33 + 8 * w + lg * 2;
        zsu[base]     = p0;              // lanes stride 33 -> conflict-free
        zsu[base + 1] = p1;
    }
    __syncthreads();

    // coalesced store: thread t -> row t>>2, uints (t&3)*8..+7 (32B/thread)
    unsigned* zo = ztu + ((size_t)bl * NN + n0) * 32;
    const int r  = tid >> 2;
    const int c0 = (tid & 3) * 8;
    const unsigned* srow = &zsu[r * 33 + c0];
    uint4 v0, v1;
    v0.x = srow[0]; v0.y = srow[1]; v0.z = srow[2]; v0.w = srow[3];
    v1.x = srow[4]; v1.y = srow[5]; v1.z = srow[6]; v1.w = srow[7];
    *(uint4*)(zo + (size_t)r * 32 + c0)     = v0;
    *(uint4*)(zo + (size_t)r * 32 + c0 + 4) = v1;
}

// ---------------------------------------------------------------------------
// k3 (v5): fp16 packed accumulation. lane = (g = lane>>4 neighbor slot,
//   cp4 = lane&15 channel quad). Slot g owns contiguous neighbors [8g,8g+8):
//   2 int4 edge loads (was 8 scalar), 8 independent uint2 gathers, 16
//   v_pk_add_f16 (was 64 unpack VALU), packed shfl_xor reduce over g.
//   XCD pinning kept (proved: FETCH 205 -> 12.4 MB). 2048 blocks x 32 pts.
// ---------------------------------------------------------------------------
template <int ZB>
__global__ __launch_bounds__(256) void k3_gather(const unsigned* __restrict__ ztu,
                                                 const int* __restrict__ edges,
                                                 float* __restrict__ hout,
                                                 float* __restrict__ p1,
                                                 float* __restrict__ p2,
                                                 int b0) {
    __shared__ float otile[64 * 33];     // 8.4 KB (channel-major, 32 points)
    __shared__ float red1[4][64][4];     // 4 KB
    __shared__ float red2[4][64][4];     // 4 KB
    const int tid  = threadIdx.x;
    const int lane = tid & 63;
    const int w    = tid >> 6;
    const int cp4  = lane & 15;          // channel quad: channels 4*cp4..+3
    const int g    = lane >> 4;          // neighbor slot: neighbors 8g..8g+7
    int bl, chunk;
    if (ZB == 4) {
        const int xcd = blockIdx.x & 7;
        bl    = xcd & 3;                               // batch pinned per XCD
        chunk = (((blockIdx.x >> 2) & 1) << 8) | (blockIdx.x >> 3);  // 0..511
    } else {
        bl = 0;
        chunk = blockIdx.x;                            // 512 blocks per batch
    }
    const int b  = b0 + bl;
    const int n0 = chunk << 5;                         // 32 points per block
    const uint2* zb2 = (const uint2*)(ztu + (size_t)bl * NN * 32);
    float s1q0 = 0.f, s1q1 = 0.f, s1q2 = 0.f, s1q3 = 0.f;
    float s2q0 = 0.f, s2q1 = 0.f, s2q2 = 0.f, s2q3 = 0.f;

    for (int i = 0; i < 8; ++i) {                      // 8 points per wave
        const int pl = w * 8 + i;
        const int pg = b * NN + n0 + pl;
        const int ebase = __builtin_amdgcn_readfirstlane(pg * KK);  // uniform

        const int4 ea = *(const int4*)(edges + ebase + g * 8);      // nbrs 8g..+3
        const int4 eb = *(const int4*)(edges + ebase + g * 8 + 4);  // nbrs 8g+4..+7

        uint2 u[8];                                    // 8 gathers in flight
        u[0] = zb2[((unsigned)ea.x << 4) | (unsigned)cp4];
        u[1] = zb2[((unsigned)ea.y << 4) | (unsigned)cp4];
        u[2] = zb2[((unsigned)ea.z << 4) | (unsigned)cp4];
        u[3] = zb2[((unsigned)ea.w << 4) | (unsigned)cp4];
        u[4] = zb2[((unsigned)eb.x << 4) | (unsigned)cp4];
        u[5] = zb2[((unsigned)eb.y << 4) | (unsigned)cp4];
        u[6] = zb2[((unsigned)eb.z << 4) | (unsigned)cp4];
        u[7] = zb2[((unsigned)eb.w << 4) | (unsigned)cp4];

        f16x2 ax = {(_Float16)0.f, (_Float16)0.f};
        f16x2 ay = {(_Float16)0.f, (_Float16)0.f};
#pragma unroll
        for (int kk = 0; kk < 8; ++kk) {               // v_pk_add_f16 x2
            ax += __builtin_bit_cast(f16x2, u[kk].x);
            ay += __builtin_bit_cast(f16x2, u[kk].y);
        }
        // packed cross-lane reduce over neighbor slots (lanes xor 16, 32)
        ax += __builtin_bit_cast(f16x2, __shfl_xor(__builtin_bit_cast(int, ax), 16));
        ay += __builtin_bit_cast(f16x2, __shfl_xor(__builtin_bit_cast(int, ay), 16));
        ax += __builtin_bit_cast(f16x2, __shfl_xor(__builtin_bit_cast(int, ax), 32));
        ay += __builtin_bit_cast(f16x2, __shfl_xor(__builtin_bit_cast(int, ay), 32));

        const float h0 = (float)ax[0] * (1.0f / KK);
        const float h1 = (float)ax[1] * (1.0f / KK);
        const float h2 = (float)ay[0] * (1.0f / KK);
        const float h3 = (float)ay[1] * (1.0f / KK);
        s1q0 += h0; s2q0 += h0 * h0;
        s1q1 += h1; s2q1 += h1 * h1;
        s1q2 += h2; s2q2 += h2 * h2;
        s1q3 += h3; s2q3 += h3 * h3;
        // lane writes channel 4*cp4+g (static select on g, no dyn index)
        const float hv = (g == 0) ? h0 : (g == 1) ? h1 : (g == 2) ? h2 : h3;
        otile[(cp4 * 4 + g) * 33 + pl] = hv;           // 2-way banks = free
    }
    __syncthreads();

    // coalesced transposed store: thread t -> channel t>>2, cols (t&3)*8..+7
    {
        const int row = tid >> 2;
        const int c0  = (tid & 3) * 8;
        const float* s = &otile[row * 33 + c0];
        float4 v0, v1;
        v0.x = s[0]; v0.y = s[1]; v0.z = s[2]; v0.w = s[3];
        v1.x = s[4]; v1.y = s[5]; v1.z = s[6]; v1.w = s[7];
        float* dst = hout + (size_t)b * CC * NN + (size_t)row * NN + n0 + c0;
        *(float4*)dst       = v0;
        *(float4*)(dst + 4) = v1;
    }

    // BN partials (g-duplicates resolved by reading only g==0 lanes)
    red1[w][lane][0] = s1q0; red1[w][lane][1] = s1q1;
    red1[w][lane][2] = s1q2; red1[w][lane][3] = s1q3;
    red2[w][lane][0] = s2q0; red2[w][lane][1] = s2q1;
    red2[w][lane][2] = s2q2; red2[w][lane][3] = s2q3;
    __syncthreads();
    if (tid < 64) {                                    // channel = tid
        const int q = tid >> 2, j = tid & 3;           // lane q holds it (g=0)
        float t1 = 0.f, t2 = 0.f;
#pragma unroll
        for (int w2 = 0; w2 < 4; ++w2) {
            t1 += red1[w2][q][j];
            t2 += red2[w2][q][j];
        }
        const int pslot = (ZB == 4) ? (bl * 512 + chunk) : (b0 * 512 + chunk);
        p1[pslot * 64 + tid] = t1;
        p2[pslot * 64 + tid] = t2;
    }
}

// ---------------------------------------------------------------------------
// k4: reduce NP partials per channel -> scale/shift (biased var, eps=1e-5).
// ---------------------------------------------------------------------------
__global__ __launch_bounds__(1024) void k4_stats(const float* __restrict__ p1,
                                                 const float* __restrict__ p2,
                                                 const float* __restrict__ gamma,
                                                 const float* __restrict__ beta,
                                                 float* __restrict__ sc,
                                                 float* __restrict__ sh) {
    __shared__ float r1[1024], r2[1024];
    const int tid = threadIdx.x;
    float s1 = 0.f, s2 = 0.f;
    for (int i = tid; i < NP * 64; i += 1024) {   // channel = i & 63 constant
        s1 += p1[i];
        s2 += p2[i];
    }
    r1[tid] = s1;
    r2[tid] = s2;
    __syncthreads();
    if (tid < 64) {
        float t1 = 0.f, t2 = 0.f;
#pragma unroll
        for (int j = 0; j < 1024; j += 64) { t1 += r1[tid + j]; t2 += r2[tid + j]; }
        const float inv = 1.0f / (float)PTS;
        const float mu  = t1 * inv;
        const float var = t2 * inv - mu * mu;      // biased variance (torch BN)
        const float s   = gamma[tid] * rsqrtf(var + 1e-5f);
        sc[tid] = s;
        sh[tid] = beta[tid] - mu * s;
    }
}

// ---------------------------------------------------------------------------
// k5: in-place BN apply + LeakyReLU(0.2) on d_out, float4 vectorized.
// ---------------------------------------------------------------------------
__global__ __launch_bounds__(256) void k5_bn(float* __restrict__ out,
                                             const float* __restrict__ sc,
                                             const float* __restrict__ sh) {
    const int total4 = BB * CC * NN / 4;           // 1,048,576 float4
    for (int i = blockIdx.x * 256 + threadIdx.x; i < total4; i += gridDim.x * 256) {
        const int c = (i >> 12) & 63;              // N/4 = 4096 float4 per channel
        const float s = sc[c];
        const float t = sh[c];
        float4 v = ((const float4*)out)[i];
        float y;
        y = fmaf(v.x, s, t); v.x = y > 0.f ? y : 0.2f * y;
        y = fmaf(v.y, s, t); v.y = y > 0.f ? y : 0.2f * y;
        y = fmaf(v.z, s, t); v.z = y > 0.f ? y : 0.2f * y;
        y = fmaf(v.w, s, t); v.w = y > 0.f ? y : 0.2f * y;
        ((float4*)out)[i] = v;
    }
}

extern "C" void kernel_launch(void* const* d_in, const int* in_sizes, int n_in,
                              void* d_out, int out_size, void* d_ws, size_t ws_size,
                              hipStream_t stream) {
    const float* x     = (const float*)d_in[0];
    const int*   edges = (const int*)d_in[1];      // harness: integer inputs -> int32
    const float* W     = (const float*)d_in[2];
    const float* gamma = (const float*)d_in[3];
    const float* beta  = (const float*)d_in[4];
    float* out = (float*)d_out;

    const size_t ZT_FULL_U = (size_t)BB * NN * 32;          // fp16x2 uints, 8.4 MB
    const size_t ZT_ONE_U  = (size_t)NN * 32;               // 2.1 MB
    const size_t PARTS_F   = (size_t)NP * 64 * 2 + 128;     // p1+p2+sc+sh
    const bool full = ws_size >= (ZT_FULL_U + PARTS_F) * 4;

    unsigned* ztu = (unsigned*)d_ws;
    float* p1 = (float*)d_ws + (full ? ZT_FULL_U : ZT_ONE_U);
    float* p2 = p1 + (size_t)NP * 64;
    float* sc = p2 + (size_t)NP * 64;
    float* sh = sc + 64;

    if (full) {
        hipLaunchKernelGGL((k1_wx_t<BB>),   dim3(BB * 256), dim3(256), 0, stream,
                           x, W, ztu, 0);
        hipLaunchKernelGGL((k3_gather<BB>), dim3(2048), dim3(256), 0, stream,
                           ztu, edges, out, p1, p2, 0);
    } else {
        for (int b = 0; b < BB; ++b) {
            hipLaunchKernelGGL((k1_wx_t<1>),   dim3(256), dim3(256), 0, stream,
                               x, W, ztu, b);
            hipLaunchKernelGGL((k3_gather<1>), dim3(512), dim3(256), 0, stream,
                               ztu, edges, out, p1, p2, b);
        }
    }
    hipLaunchKernelGGL(k4_stats, dim3(1), dim3(1024), 0, stream, p1, p2, gamma, beta, sc, sh);
    hipLaunchKernelGGL(k5_bn, dim3(2048), dim3(256), 0, stream, out, sc, sh);
}

// Round 14
// 143.204 us; speedup vs baseline: 1.0212x; 1.0212x over previous
//
#include <hip/hip_runtime.h>
#include <hip/hip_bf16.h>

// Problem constants (GraphConv: B=4, C=64, N=16384, K=32)
#define BB 4
#define CC 64
#define NN 16384
#define KK 32
#define PTS (BB * NN)   // 65536 points
#define NP  2048        // BN partial slots (32 points each)

typedef __bf16 bf16x8 __attribute__((ext_vector_type(8)));
typedef float  f32x4  __attribute__((ext_vector_type(4)));
typedef unsigned uint32x4 __attribute__((ext_vector_type(4)));
typedef _Float16 f16x2 __attribute__((ext_vector_type(2)));

// ---- pack/convert helpers --------------------------------------------------
static __device__ __forceinline__ unsigned short f2bf(float f) {
    unsigned u = __builtin_bit_cast(unsigned, f);
    unsigned r = (u + 0x7fffu + ((u >> 16) & 1u)) >> 16;   // round-nearest-even
    return (unsigned short)r;
}
static __device__ __forceinline__ float bf2f(unsigned short h) {
    return __builtin_bit_cast(float, (unsigned)h << 16);
}
static __device__ __forceinline__ unsigned short f2h(float f) {
    return __builtin_bit_cast(unsigned short, (_Float16)f);   // v_cvt_f16_f32 RNE
}
static __device__ __forceinline__ bf16x8 pack8(const float* v) {
    uint32x4 u;
#pragma unroll
    for (int i = 0; i < 4; ++i)
        u[i] = (unsigned)f2bf(v[2 * i]) | ((unsigned)f2bf(v[2 * i + 1]) << 16);
    return __builtin_bit_cast(bf16x8, u);
}

// ---------------------------------------------------------------------------
// k1 (v6, MFMA + b128 LDS): zt[bl][n][o] (fp16x2) = sum_c W[o][c]*x[b][c][n].
//   Staging now stores x TRANSPOSED + pre-converted: xsT[n][c-pair] bf16x2,
//   stride 36 uints (mult of 4 -> every b128 access 16B-aligned; 4*(ln+lg)
//   start-bank pattern spreads 256 words evenly over 32 banks). Staging:
//   wave w loads c-rows [16w,16w+16) coalesced, packs pairs, 2 ds_write_b128.
//   B-fragment = ONE ds_read_b128 (was 8 ds_read_b32 + 4 packs in v5).
//   MFMA math unchanged (bf16 hi/lo W split). Epilogue packs fp16 (v5).
// ---------------------------------------------------------------------------
template <int ZB>
__global__ __launch_bounds__(256) void k1_wx_t(const float* __restrict__ x,
                                               const float* __restrict__ W,
                                               unsigned* __restrict__ ztu,
                                               int b0) {
    __shared__ unsigned xsT[64 * 36];    // 9.2 KB bf16x2, [n][c-pair]
    __shared__ unsigned zsu[64 * 33];    // 8.4 KB fp16x2 output tile
    const int tid  = threadIdx.x;
    const int lane = tid & 63;
    const int w    = tid >> 6;
    const int chunk = blockIdx.x;        // ZB*256 chunks of 64 points
    const int bl = (ZB == 4) ? (chunk >> 8) : 0;
    const int b  = b0 + bl;
    const int n0 = (chunk & 255) << 6;

    const int ln = lane & 15;            // MFMA row (A: o) / col (B,D: n)
    const int lg = lane >> 4;            // MFMA k-group (A,B) / row-group (D)

    // A fragments: o = 16w+ln, c = 32h + lg*8 + j. hi=bf16(W), lo=bf16(W-hi).
    bf16x8 a_hi[2], a_lo[2];
    {
        const float* wr = W + (16 * w + ln) * 64 + lg * 8;
#pragma unroll
        for (int h = 0; h < 2; ++h) {
            float vhi[8], vlo[8];
#pragma unroll
            for (int j = 0; j < 8; ++j) {
                const float v  = wr[h * 32 + j];
                const float fh = bf2f(f2bf(v));
                vhi[j] = fh;
                vlo[j] = v - fh;
            }
            a_hi[h] = pack8(vhi);
            a_lo[h] = pack8(vlo);
        }
    }

    // stage: wave w loads c-rows [16w,16w+16) (coalesced), packs bf16 pairs,
    // writes its n-row slice with 2x ds_write_b128 (evenly banked).
    {
        const float* xb = x + (size_t)b * CC * NN + n0;
        float xv[16];
#pragma unroll
        for (int j = 0; j < 16; ++j)
            xv[j] = xb[(size_t)(16 * w + j) * NN + lane];
        uint32x4 u0, u1;
#pragma unroll
        for (int k2 = 0; k2 < 4; ++k2) {
            u0[k2] = (unsigned)f2bf(xv[2 * k2]) | ((unsigned)f2bf(xv[2 * k2 + 1]) << 16);
            u1[k2] = (unsigned)f2bf(xv[8 + 2 * k2]) | ((unsigned)f2bf(xv[9 + 2 * k2]) << 16);
        }
        *(uint32x4*)&xsT[lane * 36 + 8 * w]     = u0;
        *(uint32x4*)&xsT[lane * 36 + 8 * w + 4] = u1;
    }
    __syncthreads();

    // 4 n-subtiles x (k-half h) x (hi,lo): B-frag = one ds_read_b128
    f32x4 acc[4];
#pragma unroll
    for (int nt = 0; nt < 4; ++nt) acc[nt] = {0.f, 0.f, 0.f, 0.f};

#pragma unroll
    for (int nt = 0; nt < 4; ++nt) {
#pragma unroll
        for (int h = 0; h < 2; ++h) {
            const uint32x4 bu = *(const uint32x4*)&xsT[(nt * 16 + ln) * 36 + h * 16 + lg * 4];
            const bf16x8 bfrag = __builtin_bit_cast(bf16x8, bu);
            acc[nt] = __builtin_amdgcn_mfma_f32_16x16x32_bf16(a_hi[h], bfrag, acc[nt], 0, 0, 0);
            acc[nt] = __builtin_amdgcn_mfma_f32_16x16x32_bf16(a_lo[h], bfrag, acc[nt], 0, 0, 0);
        }
    }

    // epilogue: lane holds z[o = 16w + lg*4 + r][n = n0 + nt*16 + ln], r=0..3
#pragma unroll
    for (int nt = 0; nt < 4; ++nt) {
        const unsigned p0 = (unsigned)f2h(acc[nt][0]) | ((unsigned)f2h(acc[nt][1]) << 16);
        const unsigned p1 = (unsigned)f2h(acc[nt][2]) | ((unsigned)f2h(acc[nt][3]) << 16);
        const int base = (nt * 16 + ln) * 33 + 8 * w + lg * 2;
        zsu[base]     = p0;              // lanes stride 33 -> conflict-free
        zsu[base + 1] = p1;
    }
    __syncthreads();

    // coalesced store: thread t -> row t>>2, uints (t&3)*8..+7 (32B/thread)
    unsigned* zo = ztu + ((size_t)bl * NN + n0) * 32;
    const int r  = tid >> 2;
    const int c0 = (tid & 3) * 8;
    const unsigned* srow = &zsu[r * 33 + c0];
    uint4 v0, v1;
    v0.x = srow[0]; v0.y = srow[1]; v0.z = srow[2]; v0.w = srow[3];
    v1.x = srow[4]; v1.y = srow[5]; v1.z = srow[6]; v1.w = srow[7];
    *(uint4*)(zo + (size_t)r * 32 + c0)     = v0;
    *(uint4*)(zo + (size_t)r * 32 + c0 + 4) = v1;
}

// ---------------------------------------------------------------------------
// k3 (v6): 2-point pairs -> 16 independent gathers in flight (v5's 8-deep
//   was flat vs v4 => not issue-bound; this doubles memory-level parallelism
//   to test the latency hypothesis directly). Edge base of point 1 is a
//   scalar +KK from point 0. Everything else = v5 (fp16 pk_add, XCD pinning).
// ---------------------------------------------------------------------------
template <int ZB>
__global__ __launch_bounds__(256) void k3_gather(const unsigned* __restrict__ ztu,
                                                 const int* __restrict__ edges,
                                                 float* __restrict__ hout,
                                                 float* __restrict__ p1,
                                                 float* __restrict__ p2,
                                                 int b0) {
    __shared__ float otile[64 * 33];     // 8.4 KB (channel-major, 32 points)
    __shared__ float red1[4][64][4];     // 4 KB
    __shared__ float red2[4][64][4];     // 4 KB
    const int tid  = threadIdx.x;
    const int lane = tid & 63;
    const int w    = tid >> 6;
    const int cp4  = lane & 15;          // channel quad: channels 4*cp4..+3
    const int g    = lane >> 4;          // neighbor slot: neighbors 8g..8g+7
    int bl, chunk;
    if (ZB == 4) {
        const int xcd = blockIdx.x & 7;
        bl    = xcd & 3;                               // batch pinned per XCD
        chunk = (((blockIdx.x >> 2) & 1) << 8) | (blockIdx.x >> 3);  // 0..511
    } else {
        bl = 0;
        chunk = blockIdx.x;                            // 512 blocks per batch
    }
    const int b  = b0 + bl;
    const int n0 = chunk << 5;                         // 32 points per block
    const uint2* zb2 = (const uint2*)(ztu + (size_t)bl * NN * 32);
    float s1q0 = 0.f, s1q1 = 0.f, s1q2 = 0.f, s1q3 = 0.f;
    float s2q0 = 0.f, s2q1 = 0.f, s2q2 = 0.f, s2q3 = 0.f;

    for (int i = 0; i < 4; ++i) {                      // 2 points per iter
        const int pl0 = w * 8 + 2 * i;
        const int pg0 = b * NN + n0 + pl0;
        const int eb0 = __builtin_amdgcn_readfirstlane(pg0 * KK);
        const int eb1 = eb0 + KK;                      // next point, scalar add

        const int4 ea0 = *(const int4*)(edges + eb0 + g * 8);
        const int4 ec0 = *(const int4*)(edges + eb0 + g * 8 + 4);
        const int4 ea1 = *(const int4*)(edges + eb1 + g * 8);
        const int4 ec1 = *(const int4*)(edges + eb1 + g * 8 + 4);

        uint2 u0[8], u1[8];                            // 16 gathers in flight
        u0[0] = zb2[((unsigned)ea0.x << 4) | (unsigned)cp4];
        u0[1] = zb2[((unsigned)ea0.y << 4) | (unsigned)cp4];
        u0[2] = zb2[((unsigned)ea0.z << 4) | (unsigned)cp4];
        u0[3] = zb2[((unsigned)ea0.w << 4) | (unsigned)cp4];
        u0[4] = zb2[((unsigned)ec0.x << 4) | (unsigned)cp4];
        u0[5] = zb2[((unsigned)ec0.y << 4) | (unsigned)cp4];
        u0[6] = zb2[((unsigned)ec0.z << 4) | (unsigned)cp4];
        u0[7] = zb2[((unsigned)ec0.w << 4) | (unsigned)cp4];
        u1[0] = zb2[((unsigned)ea1.x << 4) | (unsigned)cp4];
        u1[1] = zb2[((unsigned)ea1.y << 4) | (unsigned)cp4];
        u1[2] = zb2[((unsigned)ea1.z << 4) | (unsigned)cp4];
        u1[3] = zb2[((unsigned)ea1.w << 4) | (unsigned)cp4];
        u1[4] = zb2[((unsigned)ec1.x << 4) | (unsigned)cp4];
        u1[5] = zb2[((unsigned)ec1.y << 4) | (unsigned)cp4];
        u1[6] = zb2[((unsigned)ec1.z << 4) | (unsigned)cp4];
        u1[7] = zb2[((unsigned)ec1.w << 4) | (unsigned)cp4];

        f16x2 ax0 = {(_Float16)0.f, (_Float16)0.f}, ay0 = ax0;
        f16x2 ax1 = ax0, ay1 = ax0;
#pragma unroll
        for (int kk = 0; kk < 8; ++kk) {               // v_pk_add_f16
            ax0 += __builtin_bit_cast(f16x2, u0[kk].x);
            ay0 += __builtin_bit_cast(f16x2, u0[kk].y);
            ax1 += __builtin_bit_cast(f16x2, u1[kk].x);
            ay1 += __builtin_bit_cast(f16x2, u1[kk].y);
        }
        // packed cross-lane reduce over neighbor slots (lanes xor 16, 32)
        ax0 += __builtin_bit_cast(f16x2, __shfl_xor(__builtin_bit_cast(int, ax0), 16));
        ay0 += __builtin_bit_cast(f16x2, __shfl_xor(__builtin_bit_cast(int, ay0), 16));
        ax1 += __builtin_bit_cast(f16x2, __shfl_xor(__builtin_bit_cast(int, ax1), 16));
        ay1 += __builtin_bit_cast(f16x2, __shfl_xor(__builtin_bit_cast(int, ay1), 16));
        ax0 += __builtin_bit_cast(f16x2, __shfl_xor(__builtin_bit_cast(int, ax0), 32));
        ay0 += __builtin_bit_cast(f16x2, __shfl_xor(__builtin_bit_cast(int, ay0), 32));
        ax1 += __builtin_bit_cast(f16x2, __shfl_xor(__builtin_bit_cast(int, ax1), 32));
        ay1 += __builtin_bit_cast(f16x2, __shfl_xor(__builtin_bit_cast(int, ay1), 32));

        const float h00 = (float)ax0[0] * (1.0f / KK);
        const float h01 = (float)ax0[1] * (1.0f / KK);
        const float h02 = (float)ay0[0] * (1.0f / KK);
        const float h03 = (float)ay0[1] * (1.0f / KK);
        const float h10 = (float)ax1[0] * (1.0f / KK);
        const float h11 = (float)ax1[1] * (1.0f / KK);
        const float h12 = (float)ay1[0] * (1.0f / KK);
        const float h13 = (float)ay1[1] * (1.0f / KK);
        s1q0 += h00 + h10; s2q0 += h00 * h00 + h10 * h10;
        s1q1 += h01 + h11; s2q1 += h01 * h01 + h11 * h11;
        s1q2 += h02 + h12; s2q2 += h02 * h02 + h12 * h12;
        s1q3 += h03 + h13; s2q3 += h03 * h03 + h13 * h13;
        // lane writes channel 4*cp4+g for both points (static select on g)
        const float hv0 = (g == 0) ? h00 : (g == 1) ? h01 : (g == 2) ? h02 : h03;
        const float hv1 = (g == 0) ? h10 : (g == 1) ? h11 : (g == 2) ? h12 : h13;
        otile[(cp4 * 4 + g) * 33 + pl0]     = hv0;     // 2-way banks = free
        otile[(cp4 * 4 + g) * 33 + pl0 + 1] = hv1;
    }
    __syncthreads();

    // coalesced transposed store: thread t -> channel t>>2, cols (t&3)*8..+7
    {
        const int row = tid >> 2;
        const int c0  = (tid & 3) * 8;
        const float* s = &otile[row * 33 + c0];
        float4 v0, v1;
        v0.x = s[0]; v0.y = s[1]; v0.z = s[2]; v0.w = s[3];
        v1.x = s[4]; v1.y = s[5]; v1.z = s[6]; v1.w = s[7];
        float* dst = hout + (size_t)b * CC * NN + (size_t)row * NN + n0 + c0;
        *(float4*)dst       = v0;
        *(float4*)(dst + 4) = v1;
    }

    // BN partials (g-duplicates resolved by reading only g==0 lanes)
    red1[w][lane][0] = s1q0; red1[w][lane][1] = s1q1;
    red1[w][lane][2] = s1q2; red1[w][lane][3] = s1q3;
    red2[w][lane][0] = s2q0; red2[w][lane][1] = s2q1;
    red2[w][lane][2] = s2q2; red2[w][lane][3] = s2q3;
    __syncthreads();
    if (tid < 64) {                                    // channel = tid
        const int q = tid >> 2, j = tid & 3;           // lane q holds it (g=0)
        float t1 = 0.f, t2 = 0.f;
#pragma unroll
        for (int w2 = 0; w2 < 4; ++w2) {
            t1 += red1[w2][q][j];
            t2 += red2[w2][q][j];
        }
        const int pslot = (ZB == 4) ? (bl * 512 + chunk) : (b0 * 512 + chunk);
        p1[pslot * 64 + tid] = t1;
        p2[pslot * 64 + tid] = t2;
    }
}

// ---------------------------------------------------------------------------
// k4: reduce NP partials per channel -> scale/shift (biased var, eps=1e-5).
// ---------------------------------------------------------------------------
__global__ __launch_bounds__(1024) void k4_stats(const float* __restrict__ p1,
                                                 const float* __restrict__ p2,
                                                 const float* __restrict__ gamma,
                                                 const float* __restrict__ beta,
                                                 float* __restrict__ sc,
                                                 float* __restrict__ sh) {
    __shared__ float r1[1024], r2[1024];
    const int tid = threadIdx.x;
    float s1 = 0.f, s2 = 0.f;
    for (int i = tid; i < NP * 64; i += 1024) {   // channel = i & 63 constant
        s1 += p1[i];
        s2 += p2[i];
    }
    r1[tid] = s1;
    r2[tid] = s2;
    __syncthreads();
    if (tid < 64) {
        float t1 = 0.f, t2 = 0.f;
#pragma unroll
        for (int j = 0; j < 1024; j += 64) { t1 += r1[tid + j]; t2 += r2[tid + j]; }
        const float inv = 1.0f / (float)PTS;
        const float mu  = t1 * inv;
        const float var = t2 * inv - mu * mu;      // biased variance (torch BN)
        const float s   = gamma[tid] * rsqrtf(var + 1e-5f);
        sc[tid] = s;
        sh[tid] = beta[tid] - mu * s;
    }
}

// ---------------------------------------------------------------------------
// k5: in-place BN apply + LeakyReLU(0.2) on d_out, float4 vectorized.
// ---------------------------------------------------------------------------
__global__ __launch_bounds__(256) void k5_bn(float* __restrict__ out,
                                             const float* __restrict__ sc,
                                             const float* __restrict__ sh) {
    const int total4 = BB * CC * NN / 4;           // 1,048,576 float4
    for (int i = blockIdx.x * 256 + threadIdx.x; i < total4; i += gridDim.x * 256) {
        const int c = (i >> 12) & 63;              // N/4 = 4096 float4 per channel
        const float s = sc[c];
        const float t = sh[c];
        float4 v = ((const float4*)out)[i];
        float y;
        y = fmaf(v.x, s, t); v.x = y > 0.f ? y : 0.2f * y;
        y = fmaf(v.y, s, t); v.y = y > 0.f ? y : 0.2f * y;
        y = fmaf(v.z, s, t); v.z = y > 0.f ? y : 0.2f * y;
        y = fmaf(v.w, s, t); v.w = y > 0.f ? y : 0.2f * y;
        ((float4*)out)[i] = v;
    }
}

extern "C" void kernel_launch(void* const* d_in, const int* in_sizes, int n_in,
                              void* d_out, int out_size, void* d_ws, size_t ws_size,
                              hipStream_t stream) {
    const float* x     = (const float*)d_in[0];
    const int*   edges = (const int*)d_in[1];      // harness: integer inputs -> int32
    const float* W     = (const float*)d_in[2];
    const float* gamma = (const float*)d_in[3];
    const float* beta  = (const float*)d_in[4];
    float* out = (float*)d_out;

    const size_t ZT_FULL_U = (size_t)BB * NN * 32;          // fp16x2 uints, 8.4 MB
    const size_t ZT_ONE_U  = (size_t)NN * 32;               // 2.1 MB
    const size_t PARTS_F   = (size_t)NP * 64 * 2 + 128;     // p1+p2+sc+sh
    const bool full = ws_size >= (ZT_FULL_U + PARTS_F) * 4;

    unsigned* ztu = (unsigned*)d_ws;
    float* p1 = (float*)d_ws + (full ? ZT_FULL_U : ZT_ONE_U);
    float* p2 = p1 + (size_t)NP * 64;
    float* sc = p2 + (size_t)NP * 64;
    float* sh = sc + 64;

    if (full) {
        hipLaunchKernelGGL((k1_wx_t<BB>),   dim3(BB * 256), dim3(256), 0, stream,
                           x, W, ztu, 0);
        hipLaunchKernelGGL((k3_gather<BB>), dim3(2048), dim3(256), 0, stream,
                           ztu, edges, out, p1, p2, 0);
    } else {
        for (int b = 0; b < BB; ++b) {
            hipLaunchKernelGGL((k1_wx_t<1>),   dim3(256), dim3(256), 0, stream,
                               x, W, ztu, b);
            hipLaunchKernelGGL((k3_gather<1>), dim3(512), dim3(256), 0, stream,
                               ztu, edges, out, p1, p2, b);
        }
    }
    hipLaunchKernelGGL(k4_stats, dim3(1), dim3(1024), 0, stream, p1, p2, gamma, beta, sc, sh);
    hipLaunchKernelGGL(k5_bn, dim3(2048), dim3(256), 0, stream, out, sc, sh);
}